// Round 1
// baseline (222.402 us; speedup 1.0000x reference)
//
#include <hip/hip_runtime.h>

#define THREADS 256
#define ITEMS 4            // float4s per thread: 64B load + 64B store per thread
#define MAGIC 0x1ACEB00Cu

// ws layout: flags[0 .. 1023]    = p1 slots (64 slots, stride 16 uints = 64B apart)
//            flags[1024 .. 2047] = p2 slots
// "Set" is encoded as the value MAGIC; anything else (0xAAAAAAAA poison, 0)
// means "not set". The harness re-poisons d_ws to 0xAA before every timed
// launch, so no init kernel is needed.
//
// NOTE (measured r0): timed window = ~160us of harness 512MiB ws-poison fills
// (2 x ~79us @ 6.75 TB/s, visible in rocprof top-5) + main (~45us) + fixup
// (~5us). Controllable slice is ~55us with a ~42us BW floor (256 MiB traffic).

typedef float v4f __attribute__((ext_vector_type(4)));

__global__ __launch_bounds__(THREADS) void main_kernel(const v4f* __restrict__ x,
                                                       v4f* __restrict__ out,
                                                       unsigned* __restrict__ flags,
                                                       int n4) {
    int base = blockIdx.x * (THREADS * ITEMS) + threadIdx.x;
    bool p1 = false, p2 = false;
#pragma unroll
    for (int k = 0; k < ITEMS; ++k) {
        int i = base + k * THREADS;
        if (i < n4) {
            v4f v = __builtin_nontemporal_load(&x[i]);
            // layers 1-2: sequential +1 adds (must match reference fp32 rounding;
            // do NOT fold to +2.0f, and do NOT test y2>=1 in place of y4>=3)
            v4f y2 = (v + 1.0f) + 1.0f;
            __builtin_nontemporal_store(y2, &out[i]);
            // checker 1 predicate: any(y2 >= 3)
            p1 = p1 || (y2.x >= 3.0f) || (y2.y >= 3.0f) || (y2.z >= 3.0f) || (y2.w >= 3.0f);
            // hypothetical layers 4-5, then checker 2 predicate: any(y4 >= 3)
            v4f y4 = (y2 + 1.0f) + 1.0f;
            p2 = p2 || (y4.x >= 3.0f) || (y4.y >= 3.0f) || (y4.z >= 3.0f) || (y4.w >= 3.0f);
        }
    }
    int lane = threadIdx.x & 63;
    // benign race: all writers store the identical MAGIC; spread over 64 slots x 64B
    if (__any(p1) && lane == 0) flags[(blockIdx.x & 63) * 16] = MAGIC;
    if (__any(p2) && lane == 0) flags[1024 + (blockIdx.x & 63) * 16] = MAGIC;
}

__global__ __launch_bounds__(THREADS) void fixup_kernel(v4f* __restrict__ out,
                                                        const unsigned* __restrict__ flags,
                                                        int n4) {
    // Each wave's 64 lanes read all 64 slots -> wave-uniform any()
    unsigned v1 = flags[(threadIdx.x & 63) * 16];
    if (__any(v1 == MAGIC)) return;  // common case: checker 1 fired, out already correct

    unsigned v2 = flags[1024 + (threadIdx.x & 63) * 16];
    bool t2 = __any(v2 == MAGIC);  // checker 2 fired -> out = y4, else out = y5

    int stride = gridDim.x * blockDim.x;
    for (int i = blockIdx.x * blockDim.x + threadIdx.x; i < n4; i += stride) {
        v4f y2 = out[i];
        v4f r = (y2 + 1.0f) + 1.0f;   // layers 4,5
        if (!t2) r = r + 1.0f;        // layer 7
        out[i] = r;
    }
}

extern "C" void kernel_launch(void* const* d_in, const int* in_sizes, int n_in,
                              void* d_out, int out_size, void* d_ws, size_t ws_size,
                              hipStream_t stream) {
    const float* x = (const float*)d_in[0];
    float* out = (float*)d_out;
    int n = in_sizes[0];          // 4096 * 8192 = 33,554,432
    int n4 = n / 4;               // 8,388,608 float4s
    unsigned* flags = (unsigned*)d_ws;

    int per_block = THREADS * ITEMS;
    int grid = (n4 + per_block - 1) / per_block;   // 8192 blocks
    main_kernel<<<grid, THREADS, 0, stream>>>((const v4f*)x, (v4f*)out, flags, n4);

    // 1024 blocks: rare-path (checker-1-never-fires) stays correct at decent BW;
    // common case is a dispatch that early-returns after one wave-uniform flag read.
    fixup_kernel<<<1024, THREADS, 0, stream>>>((v4f*)out, flags, n4);
}